// Round 5
// baseline (327.809 us; speedup 1.0000x reference)
//
#include <hip/hip_runtime.h>

// Problem: STATE_LEN=2048, SEQ_LEN=4096, HIDDEN=2048, all fp32 inputs.
// out = softmax(out_state @ W @ history^T, axis=-1)   (bias drops out of softmax)
//
// Precision: split each fp32 operand into bf16 hi + bf16 lo; MFMA computes
// hi*hi + hi*lo + lo*hi (drop lo*lo) -> ~4e-3 output error.
//
// R5: fix the REAL occupancy limiter (grid size, not launch bounds).
//  - GEMM2: 512-thread blocks, 128x128 tile -> 512 blocks = 2/CU but 16 waves/CU
//    (4 waves/SIMD; was 2). Staging bytes/FLOP unchanged.
//  - GEMM1: 64x64 tiles, 256 threads -> 1024 blocks = 4/CU = 16 waves/CU.
//  More independent waves per SIMD hide the per-iter vmcnt(0)+barrier drain.

#define STATE_LEN 2048
#define SEQ_LEN   4096
#define HIDDEN    2048

#define BK 32  // ushorts per row (64 B)

typedef __bf16 bf16x8 __attribute__((ext_vector_type(8)));
typedef float f32x4 __attribute__((ext_vector_type(4)));

__device__ __forceinline__ unsigned short f32_to_bf16(float f) {
  unsigned u = __float_as_uint(f);
  u += 0x7FFFu + ((u >> 16) & 1u);   // round-to-nearest-even
  return (unsigned short)(u >> 16);
}
__device__ __forceinline__ float bf16_to_f32(unsigned short h) {
  return __uint_as_float(((unsigned)h) << 16);
}

__device__ __forceinline__ void gld16(const void* g, void* l) {
  __builtin_amdgcn_global_load_lds(
      (const __attribute__((address_space(1))) unsigned int*)g,
      (__attribute__((address_space(3))) unsigned int*)l,
      16, 0, 0);
}

// ---------------- fp32 -> (bf16 hi, bf16 lo) elementwise split ----------------
__global__ __launch_bounds__(256) void split_kernel(
    const float* __restrict__ in, unsigned short* __restrict__ hi,
    unsigned short* __restrict__ lo, int n) {
  int i = (blockIdx.x * 256 + threadIdx.x) * 4;
  if (i >= n) return;
  float4 v = *(const float4*)&in[i];
  ushort4 h, l;
  h.x = f32_to_bf16(v.x); l.x = f32_to_bf16(v.x - bf16_to_f32(h.x));
  h.y = f32_to_bf16(v.y); l.y = f32_to_bf16(v.y - bf16_to_f32(h.y));
  h.z = f32_to_bf16(v.z); l.z = f32_to_bf16(v.z - bf16_to_f32(h.z));
  h.w = f32_to_bf16(v.w); l.w = f32_to_bf16(v.w - bf16_to_f32(h.w));
  *(ushort4*)&hi[i] = h;
  *(ushort4*)&lo[i] = l;
}

// ------------- fp32 -> transposed (bf16 hi, bf16 lo): Wt[k][h] = W[h][k] -------------
__global__ __launch_bounds__(256) void transpose_split_kernel(
    const float* __restrict__ in, unsigned short* __restrict__ hi,
    unsigned short* __restrict__ lo, int rows, int cols) {
  __shared__ float tile[32][33];
  const int bx = blockIdx.x * 32;  // col base
  const int by = blockIdx.y * 32;  // row base
  const int tx = threadIdx.x;      // 0..31
  const int ty = threadIdx.y;      // 0..7
#pragma unroll
  for (int i = 0; i < 32; i += 8)
    tile[ty + i][tx] = in[(size_t)(by + ty + i) * cols + (bx + tx)];
  __syncthreads();
#pragma unroll
  for (int i = 0; i < 32; i += 8) {
    float x = tile[tx][ty + i];
    unsigned short h = f32_to_bf16(x);
    unsigned short l = f32_to_bf16(x - bf16_to_f32(h));
    size_t o = (size_t)(bx + ty + i) * rows + (by + tx);
    hi[o] = h;
    lo[o] = l;
  }
}

// ---------------- split-bf16 GEMM, C[m][n] = sum_k A[m][k] * B[n][k] ----------------
// A: [M,K] row-major (hi/lo bf16), B: [N,K] row-major (hi/lo bf16).
// LDS swizzle: slot (row, c) holds global 16B chunk (c ^ ((row>>1)&3)).
// Wave grid WM x WN over the BM x BN tile; THREADS = WM*WN*64.
template <int THREADS, int BM, int BN, int WM, int WN, bool SPLIT_OUT>
__global__ __launch_bounds__(THREADS, 4) void gemm_bt_split(
    const unsigned short* __restrict__ Ahi, const unsigned short* __restrict__ Alo,
    const unsigned short* __restrict__ Bhi, const unsigned short* __restrict__ Blo,
    float* __restrict__ Cf, unsigned short* __restrict__ Chi,
    unsigned short* __restrict__ Clo, int M, int N, int K) {
  constexpr int MI = BM / WM / 16;   // per-wave m-tiles
  constexpr int NI = BN / WN / 16;   // per-wave n-tiles
  constexpr int RPP = THREADS / 4;   // staged rows per pass
  __shared__ __align__(16) unsigned short sAhi[BM * BK];
  __shared__ __align__(16) unsigned short sAlo[BM * BK];
  __shared__ __align__(16) unsigned short sBhi[BN * BK];
  __shared__ __align__(16) unsigned short sBlo[BN * BK];

  const int t = threadIdx.x;
  const int tileM = blockIdx.y * BM;
  const int tileN = blockIdx.x * BN;
  const int rr = t >> 2;             // staging row within a pass
  const int cc = t & 3;              // fixed LDS 16B-slot index

  const int lane = t & 63;
  const int wave = t >> 6;
  const int wm = wave / WN;
  const int wn = wave % WN;
  const int lr = lane & 15;
  const int kqc = lane >> 4;         // fragment k-chunk (16B units)

  f32x4 acc[MI][NI] = {};

  for (int k0 = 0; k0 < K; k0 += BK) {
#pragma unroll
    for (int it = 0; it < BM / RPP; ++it) {
      const int r = it * RPP + rr;
      const int q = cc ^ ((r >> 1) & 3);            // swizzle via global addr
      const size_t ga = (size_t)(tileM + r) * K + k0 + q * 8;
      const int ls = r * BK + cc * 8;               // == wave_base + lane*16 bytes
      gld16(Ahi + ga, &sAhi[ls]);
      gld16(Alo + ga, &sAlo[ls]);
    }
#pragma unroll
    for (int it = 0; it < BN / RPP; ++it) {
      const int r = it * RPP + rr;
      const int q = cc ^ ((r >> 1) & 3);
      const size_t gb = (size_t)(tileN + r) * K + k0 + q * 8;
      const int ls = r * BK + cc * 8;
      gld16(Bhi + gb, &sBhi[ls]);
      gld16(Blo + gb, &sBlo[ls]);
    }
    __syncthreads();

    bf16x8 ah[MI], al[MI], bh[NI], bl[NI];
#pragma unroll
    for (int mi = 0; mi < MI; ++mi) {
      const int R = wm * (BM / WM) + mi * 16 + lr;
      const int off = R * BK + (kqc ^ ((R >> 1) & 3)) * 8;
      ah[mi] = *(const bf16x8*)&sAhi[off];
      al[mi] = *(const bf16x8*)&sAlo[off];
    }
#pragma unroll
    for (int ni = 0; ni < NI; ++ni) {
      const int R = wn * (BN / WN) + ni * 16 + lr;
      const int off = R * BK + (kqc ^ ((R >> 1) & 3)) * 8;
      bh[ni] = *(const bf16x8*)&sBhi[off];
      bl[ni] = *(const bf16x8*)&sBlo[off];
    }
#pragma unroll
    for (int mi = 0; mi < MI; ++mi)
#pragma unroll
      for (int ni = 0; ni < NI; ++ni) {
        acc[mi][ni] = __builtin_amdgcn_mfma_f32_16x16x32_bf16(ah[mi], bh[ni], acc[mi][ni], 0, 0, 0);
        acc[mi][ni] = __builtin_amdgcn_mfma_f32_16x16x32_bf16(ah[mi], bl[ni], acc[mi][ni], 0, 0, 0);
        acc[mi][ni] = __builtin_amdgcn_mfma_f32_16x16x32_bf16(al[mi], bh[ni], acc[mi][ni], 0, 0, 0);
      }
    __syncthreads();
  }

  // epilogue: C/D layout col=lane&15, row=(lane>>4)*4+reg
#pragma unroll
  for (int mi = 0; mi < MI; ++mi)
#pragma unroll
    for (int ni = 0; ni < NI; ++ni)
#pragma unroll
      for (int e = 0; e < 4; ++e) {
        const int row = tileM + wm * (BM / WM) + mi * 16 + (lane >> 4) * 4 + e;
        const int col = tileN + wn * (BN / WN) + ni * 16 + lr;
        const float x = acc[mi][ni][e];
        const size_t o = (size_t)row * N + col;
        if (SPLIT_OUT) {
          const unsigned short h = f32_to_bf16(x);
          Chi[o] = h;
          Clo[o] = f32_to_bf16(x - bf16_to_f32(h));
        } else {
          Cf[o] = x;
        }
      }
}

// ---------------- in-place row softmax over 4096 columns ----------------
__global__ __launch_bounds__(256) void softmax_rows(float* __restrict__ d, int cols) {
  const int row = blockIdx.x;
  float* p = d + (size_t)row * cols;
  const int t = threadIdx.x;
  const int lane = t & 63;
  const int wave = t >> 6;
  __shared__ float sred[4];

  float4 v[4];
  float m = -3.0e38f;
#pragma unroll
  for (int k = 0; k < 4; ++k) {
    v[k] = *(float4*)&p[(t + k * 256) * 4];
    m = fmaxf(m, fmaxf(fmaxf(v[k].x, v[k].y), fmaxf(v[k].z, v[k].w)));
  }
#pragma unroll
  for (int off = 32; off > 0; off >>= 1) m = fmaxf(m, __shfl_xor(m, off, 64));
  if (lane == 0) sred[wave] = m;
  __syncthreads();
  m = fmaxf(fmaxf(sred[0], sred[1]), fmaxf(sred[2], sred[3]));
  __syncthreads();

  float s = 0.f;
#pragma unroll
  for (int k = 0; k < 4; ++k) {
    v[k].x = __expf(v[k].x - m);
    v[k].y = __expf(v[k].y - m);
    v[k].z = __expf(v[k].z - m);
    v[k].w = __expf(v[k].w - m);
    s += (v[k].x + v[k].y) + (v[k].z + v[k].w);
  }
#pragma unroll
  for (int off = 32; off > 0; off >>= 1) s += __shfl_xor(s, off, 64);
  if (lane == 0) sred[wave] = s;
  __syncthreads();
  s = (sred[0] + sred[1]) + (sred[2] + sred[3]);
  const float inv = 1.0f / s;
#pragma unroll
  for (int k = 0; k < 4; ++k) {
    v[k].x *= inv; v[k].y *= inv; v[k].z *= inv; v[k].w *= inv;
    *(float4*)&p[(t + k * 256) * 4] = v[k];
  }
}

extern "C" void kernel_launch(void* const* d_in, const int* in_sizes, int n_in,
                              void* d_out, int out_size, void* d_ws, size_t ws_size,
                              hipStream_t stream) {
  const float* out_state = (const float*)d_in[0];  // [2048, 2048]
  const float* history   = (const float*)d_in[1];  // [4096, 2048]
  const float* W         = (const float*)d_in[2];  // [2048, 2048]
  // d_in[3] = b : softmax-invariant, unused.
  float* out = (float*)d_out;                      // [2048, 4096] fp32

  char* ws = (char*)d_ws;
  const size_t MB = 1ull << 20;
  unsigned short* ohi  = (unsigned short*)(ws + 0 * MB);   // 8 MB  out_state hi
  unsigned short* olo  = (unsigned short*)(ws + 8 * MB);   // 8 MB  out_state lo
  unsigned short* wthi = (unsigned short*)(ws + 16 * MB);  // 8 MB  W^T hi
  unsigned short* wtlo = (unsigned short*)(ws + 24 * MB);  // 8 MB  W^T lo
  unsigned short* hhi  = (unsigned short*)(ws + 32 * MB);  // 16 MB history hi
  unsigned short* hlo  = (unsigned short*)(ws + 48 * MB);  // 16 MB history lo
  unsigned short* thi  = (unsigned short*)(ws + 64 * MB);  // 8 MB  T hi
  unsigned short* tlo  = (unsigned short*)(ws + 72 * MB);  // 8 MB  T lo

  // 1) split out_state
  split_kernel<<<(STATE_LEN * HIDDEN) / 1024, 256, 0, stream>>>(out_state, ohi, olo,
                                                                STATE_LEN * HIDDEN);
  // 2) transpose+split W -> Wt[k][h]
  transpose_split_kernel<<<dim3(HIDDEN / 32, HIDDEN / 32), dim3(32, 8), 0, stream>>>(
      W, wthi, wtlo, HIDDEN, HIDDEN);
  // 3) split history
  split_kernel<<<(SEQ_LEN * HIDDEN) / 1024, 256, 0, stream>>>(history, hhi, hlo,
                                                              SEQ_LEN * HIDDEN);
  // 4) T = out_state @ W: 64x64 tiles -> 1024 blocks (4/CU, 16 waves/CU)
  gemm_bt_split<256, 64, 64, 2, 2, true>
      <<<dim3(HIDDEN / 64, STATE_LEN / 64), 256, 0, stream>>>(
          ohi, olo, wthi, wtlo, nullptr, thi, tlo, STATE_LEN, HIDDEN, HIDDEN);
  // 5) scores = T @ history^T: 128x128 tiles, 512-thread blocks
  //    -> 512 blocks (2/CU) x 8 waves = 16 waves/CU (4/SIMD)
  gemm_bt_split<512, 128, 128, 4, 2, false>
      <<<dim3(SEQ_LEN / 128, STATE_LEN / 128), 512, 0, stream>>>(
          thi, tlo, hhi, hlo, out, nullptr, nullptr, STATE_LEN, SEQ_LEN, HIDDEN);
  // 6) row softmax in place
  softmax_rows<<<STATE_LEN, 256, 0, stream>>>(out, SEQ_LEN);
}

// Round 6
// 280.704 us; speedup vs baseline: 1.1678x; 1.1678x over previous
//
#include <hip/hip_runtime.h>

// Problem: STATE_LEN=2048, SEQ_LEN=4096, HIDDEN=2048, all fp32 inputs.
// out = softmax(out_state @ W @ history^T, axis=-1)   (bias drops out of softmax)
//
// Precision: split each fp32 operand into bf16 hi + bf16 lo; MFMA computes
// hi*hi + hi*lo + lo*hi (drop lo*lo) -> ~4e-3 output error.
//
// R6: GEMM throughput is ~ MFMAs-per-barrier (per-iter drain is fixed ~2000 cyc).
//  - GEMM1 now uses the SAME 128x128/256-thread shape as GEMM2, with K split
//    in 2 halves (grid 16x16x2 = 512 blocks = 2/CU) writing fp32 partials;
//    reduce_split sums partials -> split-bf16 T.  (R5's 64x64 tiles: 290 TF;
//    this shape: 953 TF.)
//  - GEMM2: proven R2 config (256 thr, 128x128, 64 iters, ~107 us).

#define STATE_LEN 2048
#define SEQ_LEN   4096
#define HIDDEN    2048

#define BM 128
#define BK 32

typedef __bf16 bf16x8 __attribute__((ext_vector_type(8)));
typedef float f32x4 __attribute__((ext_vector_type(4)));

__device__ __forceinline__ unsigned short f32_to_bf16(float f) {
  unsigned u = __float_as_uint(f);
  u += 0x7FFFu + ((u >> 16) & 1u);   // round-to-nearest-even
  return (unsigned short)(u >> 16);
}
__device__ __forceinline__ float bf16_to_f32(unsigned short h) {
  return __uint_as_float(((unsigned)h) << 16);
}

__device__ __forceinline__ void gld16(const void* g, void* l) {
  __builtin_amdgcn_global_load_lds(
      (const __attribute__((address_space(1))) unsigned int*)g,
      (__attribute__((address_space(3))) unsigned int*)l,
      16, 0, 0);
}

// ---------------- fp32 -> (bf16 hi, bf16 lo) elementwise split ----------------
__global__ __launch_bounds__(256) void split_kernel(
    const float* __restrict__ in, unsigned short* __restrict__ hi,
    unsigned short* __restrict__ lo, int n) {
  int i = (blockIdx.x * 256 + threadIdx.x) * 4;
  if (i >= n) return;
  float4 v = *(const float4*)&in[i];
  ushort4 h, l;
  h.x = f32_to_bf16(v.x); l.x = f32_to_bf16(v.x - bf16_to_f32(h.x));
  h.y = f32_to_bf16(v.y); l.y = f32_to_bf16(v.y - bf16_to_f32(h.y));
  h.z = f32_to_bf16(v.z); l.z = f32_to_bf16(v.z - bf16_to_f32(h.z));
  h.w = f32_to_bf16(v.w); l.w = f32_to_bf16(v.w - bf16_to_f32(h.w));
  *(ushort4*)&hi[i] = h;
  *(ushort4*)&lo[i] = l;
}

// ------------- fp32 -> transposed (bf16 hi, bf16 lo): Wt[k][h] = W[h][k] -------------
__global__ __launch_bounds__(256) void transpose_split_kernel(
    const float* __restrict__ in, unsigned short* __restrict__ hi,
    unsigned short* __restrict__ lo, int rows, int cols) {
  __shared__ float tile[32][33];
  const int bx = blockIdx.x * 32;  // col base
  const int by = blockIdx.y * 32;  // row base
  const int tx = threadIdx.x;      // 0..31
  const int ty = threadIdx.y;      // 0..7
#pragma unroll
  for (int i = 0; i < 32; i += 8)
    tile[ty + i][tx] = in[(size_t)(by + ty + i) * cols + (bx + tx)];
  __syncthreads();
#pragma unroll
  for (int i = 0; i < 32; i += 8) {
    float x = tile[tx][ty + i];
    unsigned short h = f32_to_bf16(x);
    unsigned short l = f32_to_bf16(x - bf16_to_f32(h));
    size_t o = (size_t)(bx + ty + i) * rows + (by + tx);
    hi[o] = h;
    lo[o] = l;
  }
}

// ---- p0+p1 -> split bf16 (hi/lo), elementwise over 2048x2048 ----
__global__ __launch_bounds__(256) void reduce_split(
    const float* __restrict__ p0, const float* __restrict__ p1,
    unsigned short* __restrict__ hi, unsigned short* __restrict__ lo, int n) {
  int i = (blockIdx.x * 256 + threadIdx.x) * 4;
  if (i >= n) return;
  float4 a = *(const float4*)&p0[i];
  float4 b = *(const float4*)&p1[i];
  a.x += b.x; a.y += b.y; a.z += b.z; a.w += b.w;
  ushort4 h, l;
  h.x = f32_to_bf16(a.x); l.x = f32_to_bf16(a.x - bf16_to_f32(h.x));
  h.y = f32_to_bf16(a.y); l.y = f32_to_bf16(a.y - bf16_to_f32(h.y));
  h.z = f32_to_bf16(a.z); l.z = f32_to_bf16(a.z - bf16_to_f32(h.z));
  h.w = f32_to_bf16(a.w); l.w = f32_to_bf16(a.w - bf16_to_f32(h.w));
  *(ushort4*)&hi[i] = h;
  *(ushort4*)&lo[i] = l;
}

// ---------------- split-bf16 GEMM, C[m][n] = sum_k A[m][k] * B[n][k] ----------------
// A: [M,K] row-major (hi/lo bf16), B: [N,K] row-major (hi/lo bf16).
// LDS swizzle: slot (row, c) holds global 16B chunk (c ^ ((row>>1)&3)).
// KSPLIT>1: blockIdx.z selects a K-chunk; Cf points to partial z (fp32 out).
template <int BN, bool SPLIT_OUT, int KSPLIT>
__global__ __launch_bounds__(256, 2) void gemm_bt_split(
    const unsigned short* __restrict__ Ahi, const unsigned short* __restrict__ Alo,
    const unsigned short* __restrict__ Bhi, const unsigned short* __restrict__ Blo,
    float* __restrict__ Cf, unsigned short* __restrict__ Chi,
    unsigned short* __restrict__ Clo, int M, int N, int K) {
  constexpr int NI = BN / 32;  // per-wave n-tiles (2x2 wave grid, wave n-span BN/2)
  __shared__ __align__(16) unsigned short sAhi[BM * BK];
  __shared__ __align__(16) unsigned short sAlo[BM * BK];
  __shared__ __align__(16) unsigned short sBhi[BN * BK];
  __shared__ __align__(16) unsigned short sBlo[BN * BK];

  const int t = threadIdx.x;           // 0..255 (4 waves)
  const int tileM = blockIdx.y * BM;
  const int tileN = blockIdx.x * BN;
  const int kBase = (KSPLIT > 1) ? blockIdx.z * (K / KSPLIT) : 0;
  const int kEnd = kBase + K / KSPLIT;
  if (KSPLIT > 1) Cf += (size_t)blockIdx.z * M * N;
  const int rr = t >> 2;               // staging row within a 64-row group
  const int cc = t & 3;                // this lane's fixed LDS 16B-slot index

  const int lane = t & 63;
  const int wave = t >> 6;
  const int wm = wave >> 1;            // 2x2 wave grid
  const int wn = wave & 1;
  const int lr = lane & 15;
  const int kqc = lane >> 4;           // fragment k-chunk (16B units)

  f32x4 acc[4][NI] = {};

  for (int k0 = kBase; k0 < kEnd; k0 += BK) {
    // stage A (BM=128 rows): 2 passes of 64 rows
#pragma unroll
    for (int it = 0; it < 2; ++it) {
      const int r = it * 64 + rr;
      const int q = cc ^ ((r >> 1) & 3);            // swizzle via global addr
      const size_t ga = (size_t)(tileM + r) * K + k0 + q * 8;
      const int ls = r * BK + cc * 8;               // == wave_base + lane*16 bytes
      gld16(Ahi + ga, &sAhi[ls]);
      gld16(Alo + ga, &sAlo[ls]);
    }
    // stage B (BN rows): BN/64 passes
#pragma unroll
    for (int it = 0; it < BN / 64; ++it) {
      const int r = it * 64 + rr;
      const int q = cc ^ ((r >> 1) & 3);
      const size_t gb = (size_t)(tileN + r) * K + k0 + q * 8;
      const int ls = r * BK + cc * 8;
      gld16(Bhi + gb, &sBhi[ls]);
      gld16(Blo + gb, &sBlo[ls]);
    }
    __syncthreads();

    bf16x8 ah[4], al[4], bh[NI], bl[NI];
#pragma unroll
    for (int mi = 0; mi < 4; ++mi) {
      const int R = wm * 64 + mi * 16 + lr;
      const int off = R * BK + (kqc ^ ((R >> 1) & 3)) * 8;
      ah[mi] = *(const bf16x8*)&sAhi[off];
      al[mi] = *(const bf16x8*)&sAlo[off];
    }
#pragma unroll
    for (int ni = 0; ni < NI; ++ni) {
      const int R = wn * (BN / 2) + ni * 16 + lr;
      const int off = R * BK + (kqc ^ ((R >> 1) & 3)) * 8;
      bh[ni] = *(const bf16x8*)&sBhi[off];
      bl[ni] = *(const bf16x8*)&sBlo[off];
    }
#pragma unroll
    for (int mi = 0; mi < 4; ++mi)
#pragma unroll
      for (int ni = 0; ni < NI; ++ni) {
        acc[mi][ni] = __builtin_amdgcn_mfma_f32_16x16x32_bf16(ah[mi], bh[ni], acc[mi][ni], 0, 0, 0);
        acc[mi][ni] = __builtin_amdgcn_mfma_f32_16x16x32_bf16(ah[mi], bl[ni], acc[mi][ni], 0, 0, 0);
        acc[mi][ni] = __builtin_amdgcn_mfma_f32_16x16x32_bf16(al[mi], bh[ni], acc[mi][ni], 0, 0, 0);
      }
    __syncthreads();
  }

  // epilogue: C/D layout col=lane&15, row=(lane>>4)*4+reg
#pragma unroll
  for (int mi = 0; mi < 4; ++mi)
#pragma unroll
    for (int ni = 0; ni < NI; ++ni)
#pragma unroll
      for (int e = 0; e < 4; ++e) {
        const int row = tileM + wm * 64 + mi * 16 + (lane >> 4) * 4 + e;
        const int col = tileN + wn * (BN / 2) + ni * 16 + lr;
        const float x = acc[mi][ni][e];
        const size_t o = (size_t)row * N + col;
        if (SPLIT_OUT) {
          const unsigned short h = f32_to_bf16(x);
          Chi[o] = h;
          Clo[o] = f32_to_bf16(x - bf16_to_f32(h));
        } else {
          Cf[o] = x;
        }
      }
}

// ---------------- in-place row softmax over 4096 columns ----------------
__global__ __launch_bounds__(256) void softmax_rows(float* __restrict__ d, int cols) {
  const int row = blockIdx.x;
  float* p = d + (size_t)row * cols;
  const int t = threadIdx.x;
  const int lane = t & 63;
  const int wave = t >> 6;
  __shared__ float sred[4];

  float4 v[4];
  float m = -3.0e38f;
#pragma unroll
  for (int k = 0; k < 4; ++k) {
    v[k] = *(float4*)&p[(t + k * 256) * 4];
    m = fmaxf(m, fmaxf(fmaxf(v[k].x, v[k].y), fmaxf(v[k].z, v[k].w)));
  }
#pragma unroll
  for (int off = 32; off > 0; off >>= 1) m = fmaxf(m, __shfl_xor(m, off, 64));
  if (lane == 0) sred[wave] = m;
  __syncthreads();
  m = fmaxf(fmaxf(sred[0], sred[1]), fmaxf(sred[2], sred[3]));
  __syncthreads();

  float s = 0.f;
#pragma unroll
  for (int k = 0; k < 4; ++k) {
    v[k].x = __expf(v[k].x - m);
    v[k].y = __expf(v[k].y - m);
    v[k].z = __expf(v[k].z - m);
    v[k].w = __expf(v[k].w - m);
    s += (v[k].x + v[k].y) + (v[k].z + v[k].w);
  }
#pragma unroll
  for (int off = 32; off > 0; off >>= 1) s += __shfl_xor(s, off, 64);
  if (lane == 0) sred[wave] = s;
  __syncthreads();
  s = (sred[0] + sred[1]) + (sred[2] + sred[3]);
  const float inv = 1.0f / s;
#pragma unroll
  for (int k = 0; k < 4; ++k) {
    v[k].x *= inv; v[k].y *= inv; v[k].z *= inv; v[k].w *= inv;
    *(float4*)&p[(t + k * 256) * 4] = v[k];
  }
}

extern "C" void kernel_launch(void* const* d_in, const int* in_sizes, int n_in,
                              void* d_out, int out_size, void* d_ws, size_t ws_size,
                              hipStream_t stream) {
  const float* out_state = (const float*)d_in[0];  // [2048, 2048]
  const float* history   = (const float*)d_in[1];  // [4096, 2048]
  const float* W         = (const float*)d_in[2];  // [2048, 2048]
  // d_in[3] = b : softmax-invariant, unused.
  float* out = (float*)d_out;                      // [2048, 4096] fp32

  char* ws = (char*)d_ws;
  const size_t MB = 1ull << 20;
  unsigned short* ohi  = (unsigned short*)(ws + 0 * MB);   // 8 MB  out_state hi
  unsigned short* olo  = (unsigned short*)(ws + 8 * MB);   // 8 MB  out_state lo
  unsigned short* wthi = (unsigned short*)(ws + 16 * MB);  // 8 MB  W^T hi (dead after GEMM1)
  unsigned short* wtlo = (unsigned short*)(ws + 24 * MB);  // 8 MB  W^T lo (dead after GEMM1)
  unsigned short* hhi  = (unsigned short*)(ws + 32 * MB);  // 16 MB history hi
  unsigned short* hlo  = (unsigned short*)(ws + 48 * MB);  // 16 MB history lo
  float*          part = (float*)(ws + 64 * MB);           // 32 MB: 2 x 2048x2048 fp32 partials
  unsigned short* thi  = (unsigned short*)(ws + 16 * MB);  // reuse wthi space after GEMM1
  unsigned short* tlo  = (unsigned short*)(ws + 24 * MB);  // reuse wtlo space after GEMM1

  // 1) split out_state
  split_kernel<<<(STATE_LEN * HIDDEN) / 1024, 256, 0, stream>>>(out_state, ohi, olo,
                                                                STATE_LEN * HIDDEN);
  // 2) transpose+split W -> Wt[k][h]
  transpose_split_kernel<<<dim3(HIDDEN / 32, HIDDEN / 32), dim3(32, 8), 0, stream>>>(
      W, wthi, wtlo, HIDDEN, HIDDEN);
  // 3) split history
  split_kernel<<<(SEQ_LEN * HIDDEN) / 1024, 256, 0, stream>>>(history, hhi, hlo,
                                                              SEQ_LEN * HIDDEN);
  // 4) T partials: 128x128 tiles, K split in 2 -> 16x16x2 = 512 blocks
  gemm_bt_split<128, false, 2>
      <<<dim3(HIDDEN / 128, STATE_LEN / 128, 2), 256, 0, stream>>>(
          ohi, olo, wthi, wtlo, part, nullptr, nullptr, STATE_LEN, HIDDEN, HIDDEN);
  // 4b) T = p0 + p1, split to bf16 hi/lo (overwrites dead Wt space)
  reduce_split<<<(STATE_LEN * HIDDEN) / 1024, 256, 0, stream>>>(
      part, part + (size_t)STATE_LEN * HIDDEN, thi, tlo, STATE_LEN * HIDDEN);
  // 5) scores = T @ history^T, fp32 into d_out, 128x128 tiles (proven config)
  gemm_bt_split<128, false, 1>
      <<<dim3(SEQ_LEN / 128, STATE_LEN / 128), 256, 0, stream>>>(
          thi, tlo, hhi, hlo, out, nullptr, nullptr, STATE_LEN, SEQ_LEN, HIDDEN);
  // 6) row softmax in place
  softmax_rows<<<STATE_LEN, 256, 0, stream>>>(out, SEQ_LEN);
}